// Round 4
// baseline (283.226 us; speedup 1.0000x reference)
//
#include <hip/hip_runtime.h>
#include <math.h>

#define BSZ    256
#define GRID_N 49
#define LSTMH  512
#define CNN_C  2048
#define PROJ   512
#define KAUG   2560               // [cnn k=0..2047 | lstm k=2048..2559]
#define M_TOT  12544              // 256*49 = 196*64 exactly
#define MT     64
#define NT     128
#define BK     64
#define KTILES (KAUG / BK)        // 40
#define NBLK   ((M_TOT / MT) * (PROJ / NT))   // 196*4 = 784

typedef short bf16x8 __attribute__((ext_vector_type(8)));
typedef float f32x4  __attribute__((ext_vector_type(4)));

static __device__ __forceinline__ unsigned short bf16_rne(float f) {
    unsigned int u = __float_as_uint(f);
    u = u + 0x7FFFu + ((u >> 16) & 1u);
    return (unsigned short)(u >> 16);
}
static __device__ __forceinline__ uint4 pack8f(const float* f) {
    uint4 o;
    o.x = (unsigned int)bf16_rne(f[0]) | ((unsigned int)bf16_rne(f[1]) << 16);
    o.y = (unsigned int)bf16_rne(f[2]) | ((unsigned int)bf16_rne(f[3]) << 16);
    o.z = (unsigned int)bf16_rne(f[4]) | ((unsigned int)bf16_rne(f[5]) << 16);
    o.w = (unsigned int)bf16_rne(f[6]) | ((unsigned int)bf16_rne(f[7]) << 16);
    return o;
}
static __device__ __forceinline__ float tanh_fast(float x) {
    float e = __expf(2.f * x);
    return 1.f - 2.f / (e + 1.f);
}

// ---- Prep: W_aug (512 x 2560) fp32 -> bf16(RNE) into d_ws (proven r2/r3) ----
__global__ __launch_bounds__(256) void prep_w(const float* __restrict__ Wc,
                                              const float* __restrict__ Wl,
                                              unsigned short* __restrict__ wsW) {
    int c  = blockIdx.x * 256 + threadIdx.x;   // 512*320 chunks exactly
    int p  = c / 320;
    int kc = (c % 320) * 8;
    const float* src = (kc < CNN_C) ? (Wc + (size_t)p * CNN_C + kc)
                                    : (Wl + (size_t)p * LSTMH + (kc - CNN_C));
    float f[8];
    *(float4*)&f[0] = ((const float4*)src)[0];
    *(float4*)&f[4] = ((const float4*)src)[1];
    *(uint4*)(wsW + (size_t)p * KAUG + kc) = pack8f(f);
}

// ---- Main GEMM: 64x128 tile. A (cnn|lstm rows, bf16-hi) staged in dbuf LDS;
// B fragments loaded per-wave global->VGPR (bf16 W in ws, L2-resident), ping-pong.
// One barrier per K-tile. Epilogue: tanh + w_attn partial dot over 128 cols,
// atomicAdd into scrambled out[g*BSZ+b] (pre-zeroed).
template <bool WS>
__global__ __launch_bounds__(256, 3) void gemm_k(
    const float* __restrict__ lstm, const float* __restrict__ cnn,
    const float* __restrict__ Wc,   const float* __restrict__ Wl,
    const float* __restrict__ bl,   const float* __restrict__ bc,
    const float* __restrict__ wat,  const unsigned short* __restrict__ wsW,
    float* __restrict__ out)
{
    __shared__ unsigned short Ash[2][MT][BK];   // 16 KB double-buffered A
    __shared__ float zp[4][MT];                 // 1 KB

    const int t   = threadIdx.x;
    const int w   = t >> 6;
    const int l   = t & 63;
    const int q   = l >> 4;
    const int r16 = l & 15;

    const int m0 = (int)(blockIdx.x >> 2) * MT;
    const int n0 = (int)(blockIdx.x & 3) * NT;

    // ---- A staging identity: thread t owns row ra, floats [ca*16, ca*16+16) ----
    const int ra = t >> 2;
    const int ca = t & 3;
    const int sw = ra & 7;
    const int grow = m0 + ra;
    const int ab   = grow / 49;
    const int ag   = grow - ab * 49;
    const float* cnnb  = cnn + ((size_t)ab * GRID_N + ag) * CNN_C;
    const float* lstmb = lstm + (size_t)ab * LSTMH;

    // ---- B fragment identity: lane holds W_aug[n][k..k+8) ----
    const int bn = n0 + w * 32 + r16;     // + nt*16
    const int bk = q * 8;                 // + ks*32 + k0

    f32x4 acc[4][2];
    #pragma unroll
    for (int mt = 0; mt < 4; ++mt)
        #pragma unroll
        for (int nt = 0; nt < 2; ++nt)
            acc[mt][nt] = (f32x4){0.f, 0.f, 0.f, 0.f};

    float4 fa[4];                 // A fp32 prefetch (16 floats)
    bf16x8 Breg[2][2][2];         // [pingpong][nt][ks]

    auto a_load = [&](int k0) {
        const float* s = (k0 < CNN_C) ? (cnnb + k0) : (lstmb + (k0 - CNN_C));
        const float4* p = (const float4*)(s + ca * 16);
        fa[0] = p[0]; fa[1] = p[1]; fa[2] = p[2]; fa[3] = p[3];
    };
    auto a_write = [&](int buf) {
        float f[16];
        *(float4*)&f[0]  = fa[0]; *(float4*)&f[4]  = fa[1];
        *(float4*)&f[8]  = fa[2]; *(float4*)&f[12] = fa[3];
        *(uint4*)&Ash[buf][ra][((2 * ca) ^ sw) * 8]     = pack8f(&f[0]);
        *(uint4*)&Ash[buf][ra][((2 * ca + 1) ^ sw) * 8] = pack8f(&f[8]);
    };
    auto b_load = [&](int k0, int pp) {
        #pragma unroll
        for (int nt = 0; nt < 2; ++nt)
            #pragma unroll
            for (int ks = 0; ks < 2; ++ks) {
                if constexpr (WS) {
                    Breg[pp][nt][ks] = *(const bf16x8*)(
                        wsW + (size_t)(bn + nt * 16) * KAUG + k0 + ks * 32 + bk);
                } else {
                    const int kk = k0 + ks * 32 + bk;
                    const int n  = bn + nt * 16;
                    const float* s = (kk < CNN_C) ? (Wc + (size_t)n * CNN_C + kk)
                                                  : (Wl + (size_t)n * LSTMH + (kk - CNN_C));
                    float f[8];
                    *(float4*)&f[0] = ((const float4*)s)[0];
                    *(float4*)&f[4] = ((const float4*)s)[1];
                    uint4 u = pack8f(f);
                    Breg[pp][nt][ks] = *(bf16x8*)&u;
                }
            }
    };
    auto compute = [&](int buf, int pp) {
        #pragma unroll
        for (int ks = 0; ks < 2; ++ks) {
            const int cp = ((ks * 4 + q) ^ (r16 & 7)) * 8;
            bf16x8 af[4];
            #pragma unroll
            for (int mt = 0; mt < 4; ++mt)
                af[mt] = *(const bf16x8*)&Ash[buf][mt * 16 + r16][cp];
            #pragma unroll
            for (int mt = 0; mt < 4; ++mt)
                #pragma unroll
                for (int nt = 0; nt < 2; ++nt)
                    acc[mt][nt] = __builtin_amdgcn_mfma_f32_16x16x32_bf16(
                        af[mt], Breg[pp][nt][ks], acc[mt][nt], 0, 0, 0);
        }
    };

    // ---- prologue ----
    a_load(0);
    b_load(0, 0);
    a_write(0);
    __syncthreads();

    // ---- K loop, unrolled x2 for compile-time buffer indices ----
    for (int kt = 0; kt < KTILES; kt += 2) {
        // tile kt (buf0, pp0); kt+1 always exists (KTILES even)
        a_load((kt + 1) * BK);
        b_load((kt + 1) * BK, 1);
        compute(0, 0);
        a_write(1);
        __syncthreads();
        // tile kt+1 (buf1, pp1)
        const bool more = (kt + 2 < KTILES);
        if (more) {
            a_load((kt + 2) * BK);
            b_load((kt + 2) * BK, 0);
        }
        compute(1, 1);
        if (more) a_write(0);
        __syncthreads();
    }

    // ---- epilogue: tanh + w_attn partial dot over this block's 128 cols ----
    float part[4][4];
    #pragma unroll
    for (int mt = 0; mt < 4; ++mt)
        #pragma unroll
        for (int rr = 0; rr < 4; ++rr) part[mt][rr] = 0.f;
    #pragma unroll
    for (int nt = 0; nt < 2; ++nt) {
        const int p = n0 + w * 32 + nt * 16 + r16;
        const float bb = bl[p] + bc[p];
        const float wa = wat[p];
        #pragma unroll
        for (int mt = 0; mt < 4; ++mt)
            #pragma unroll
            for (int rr = 0; rr < 4; ++rr)
                part[mt][rr] += tanh_fast(acc[mt][nt][rr] + bb) * wa;
    }
    #pragma unroll
    for (int mt = 0; mt < 4; ++mt)
        #pragma unroll
        for (int rr = 0; rr < 4; ++rr) {
            float v = part[mt][rr];
            v += __shfl_xor(v, 1);
            v += __shfl_xor(v, 2);
            v += __shfl_xor(v, 4);
            v += __shfl_xor(v, 8);            // sum over the 16 cols (r16 group)
            if (r16 == 0) zp[w][mt * 16 + q * 4 + rr] = v;
        }
    __syncthreads();
    if (t < MT) {
        const float v = zp[0][t] + zp[1][t] + zp[2][t] + zp[3][t];
        const int row = m0 + t;
        const int b2  = row / 49;
        const int g2  = row - b2 * 49;
        atomicAdd(&out[g2 * BSZ + b2], v);    // scrambled position
    }
}

// Row softmax over 49 elements, in place. One wave per row.
__global__ __launch_bounds__(64) void softmax_rows(float* __restrict__ out)
{
    const int i = blockIdx.x;
    const int j = threadIdx.x;
    float x = (j < GRID_N) ? out[i * GRID_N + j] : -1e30f;
    float m = x;
    #pragma unroll
    for (int off = 32; off > 0; off >>= 1) m = fmaxf(m, __shfl_xor(m, off));
    float e = (j < GRID_N) ? __expf(x - m) : 0.f;
    float s = e;
    #pragma unroll
    for (int off = 32; off > 0; off >>= 1) s += __shfl_xor(s, off);
    if (j < GRID_N) out[i * GRID_N + j] = e / s;
}

extern "C" void kernel_launch(void* const* d_in, const int* in_sizes, int n_in,
                              void* d_out, int out_size, void* d_ws, size_t ws_size,
                              hipStream_t stream)
{
    const float* lstm = (const float*)d_in[0];
    const float* cnn  = (const float*)d_in[1];
    const float* Wl   = (const float*)d_in[2];
    const float* bl   = (const float*)d_in[3];
    const float* Wc   = (const float*)d_in[4];
    const float* bc   = (const float*)d_in[5];
    const float* wat  = (const float*)d_in[6];
    float* out = (float*)d_out;

    hipMemsetAsync(out, 0, (size_t)out_size * sizeof(float), stream);

    const size_t wneed = (size_t)PROJ * KAUG * sizeof(unsigned short);  // 2.62 MB
    if (ws_size >= wneed) {
        unsigned short* wsW = (unsigned short*)d_ws;
        prep_w<<<dim3(640), dim3(256), 0, stream>>>(Wc, Wl, wsW);
        gemm_k<true><<<dim3(NBLK), dim3(256), 0, stream>>>(lstm, cnn, Wc, Wl, bl, bc, wat, wsW, out);
    } else {
        gemm_k<false><<<dim3(NBLK), dim3(256), 0, stream>>>(lstm, cnn, Wc, Wl, bl, bc, wat, nullptr, out);
    }
    softmax_rows<<<dim3(BSZ), dim3(64), 0, stream>>>(out);
}